// Round 10
// baseline (297.214 us; speedup 1.0000x reference)
//
#include <hip/hip_runtime.h>
#include <hip/hip_bf16.h>
#include <stdint.h>

typedef unsigned short u16;
typedef __attribute__((ext_vector_type(8))) __bf16 bf16x8;
typedef __attribute__((ext_vector_type(4))) float f32x4;
typedef __attribute__((ext_vector_type(4))) float float4v;
typedef __attribute__((ext_vector_type(4))) u16  u16x4;
typedef __attribute__((ext_vector_type(8))) u16  u16x8;

#define DEV __device__ __forceinline__

#define NB   2
#define CUR  1024
#define PREV 1024
#define TOT  2048
#define DM   1024
#define NH   16
#define DH   64

DEV u16 f2b(float f) {
    uint32_t u = __builtin_bit_cast(uint32_t, f);
    uint32_t r = (u + 0x7fffu + ((u >> 16) & 1u)) >> 16;   // RNE
    return (u16)r;
}
DEV float b2f(u16 u) {
    return __builtin_bit_cast(float, (uint32_t)u << 16);
}

typedef const __attribute__((address_space(1))) void* gptr_t;
typedef __attribute__((address_space(3))) void*       lptr_t;
DEV void async16(const void* g, void* l) {
    __builtin_amdgcn_global_load_lds((gptr_t)g, (lptr_t)l, 16, 0, 0);
}

// ---------------------------------------------------------------------------
// bf16 MFMA GEMM, transposed-output convention (C^T = A[M,K]*B[N,K]^T, M = the
// contiguous output dim). LDS XOR-swizzled via pre-swizzled global source.
// EPI: 1=Q->Abuf(+u,+v,shift)  2=KV->Bbuf/Vtmp  5=final(+x+bfc)->Yf
// ---------------------------------------------------------------------------
template<int BM, int BN, int BK, int WM, int WN, int EPI>
__global__ __launch_bounds__(256)
void gemm_bt(const u16* __restrict__ A, const u16* __restrict__ B,
             int M, int N, int K, long sA, long sB, int bzBase,
             void* __restrict__ C0, void* __restrict__ C1,
             const float* __restrict__ F0, const float* __restrict__ F1)
{
    constexpr int WAVES_N = BN / WN;
    constexpr int MI = WM / 16, NI = WN / 16;
    static_assert((BM / WM) * (BN / WN) == 4, "4 waves");
    static_assert(BK == 64, "swizzle assumes 8 chunks/row");

    __shared__ u16 lA[BM * BK];
    __shared__ u16 lB[BN * BK];

    const int bz = blockIdx.z;
    const int m0 = blockIdx.y * BM, n0 = blockIdx.x * BN;
    const int tid = threadIdx.x, wave = tid >> 6, lane = tid & 63;

    const u16* Ab = A + (long)bz * sA;
    const u16* Bb = B + (long)bz * sB;
    const int wm0 = (wave / WAVES_N) * WM, wn0 = (wave % WAVES_N) * WN;
    const int quad = lane >> 4;

    f32x4 acc[MI][NI];
#pragma unroll
    for (int mi = 0; mi < MI; ++mi)
#pragma unroll
        for (int ni = 0; ni < NI; ++ni)
            acc[mi][ni] = f32x4{0.f, 0.f, 0.f, 0.f};

    const int srow = tid >> 3;
    const int ksw  = (((tid & 7) ^ ((tid >> 3) & 7)) << 3);

    for (int kt = 0; kt < K; kt += BK) {
        __syncthreads();
#pragma unroll
        for (int is = 0; is < (BM * BK) / 2048; ++is) {
            int r = is * 32 + srow;
            async16(Ab + (long)(m0 + r) * K + kt + ksw, &lA[is * 2048 + wave * 512]);
        }
#pragma unroll
        for (int is = 0; is < (BN * BK) / 2048; ++is) {
            int r = is * 32 + srow;
            async16(Bb + (long)(n0 + r) * K + kt + ksw, &lB[is * 2048 + wave * 512]);
        }
        __syncthreads();
#pragma unroll
        for (int ks = 0; ks < BK; ks += 32) {
            bf16x8 af[MI], br[NI];
#pragma unroll
            for (int mi = 0; mi < MI; ++mi)
                af[mi] = *(const bf16x8*)(const void*)
                    &lA[(wm0 + mi * 16 + (lane & 15)) * BK +
                        ((((ks >> 3) + quad) ^ (lane & 7)) << 3)];
#pragma unroll
            for (int ni = 0; ni < NI; ++ni)
                br[ni] = *(const bf16x8*)(const void*)
                    &lB[(wn0 + ni * 16 + (lane & 15)) * BK +
                        ((((ks >> 3) + quad) ^ (lane & 7)) << 3)];
#pragma unroll
            for (int mi = 0; mi < MI; ++mi)
#pragma unroll
                for (int ni = 0; ni < NI; ++ni)
                    acc[mi][ni] = __builtin_amdgcn_mfma_f32_16x16x32_bf16(af[mi], br[ni], acc[mi][ni], 0, 0, 0);
        }
    }

    const int gbz = bzBase + bz;

    if constexpr (EPI == 1) {                 // m = h*64+d, n = token i, bz = b
        u16* Abuf = (u16*)C0;
        const int b = gbz;
#pragma unroll
        for (int mi = 0; mi < MI; ++mi) {
            const int m = m0 + wm0 + mi * 16 + quad * 4;
            const int h = m >> 6, d = m & 63;
            const float4v uu = *(const float4v*)(F0 + m);
            const float4v vv = *(const float4v*)(F1 + m);
#pragma unroll
            for (int ni = 0; ni < NI; ++ni) {
                const int i = n0 + wn0 + ni * 16 + (lane & 15);
                u16x4 pu, pv;
#pragma unroll
                for (int r = 0; r < 4; ++r) {
                    pu[r] = f2b(acc[mi][ni][r] + uu[r]);
                    pv[r] = f2b(acc[mi][ni][r] + vv[r]);
                }
                *(u16x4*)(Abuf + (((long)(b * NH + h)) * CUR + i) * 128 + d) = pu;
                if (b == 0) {
                    if (i > 0)
                        *(u16x4*)(Abuf + (((long)h) * CUR + (i - 1)) * 128 + 64 + d) = pv;
                    if (i == 1023) {
                        u16x4 z = {};
                        *(u16x4*)(Abuf + (((long)h) * CUR + 1023) * 128 + 64 + d) = z;
                    }
                } else {
                    *(u16x4*)(Abuf + (((long)(NH + h)) * CUR + i) * 128 + 64 + d) = pv;
                }
            }
        }
    } else if constexpr (EPI == 2) {          // m = out-ch (k|v), n = b*2048+j
#pragma unroll
        for (int mi = 0; mi < MI; ++mi) {
            const int m = m0 + wm0 + mi * 16 + quad * 4;
            const bool isV = m >= DM;
            const int h = (m >> 6) & 15, d = m & 63;
#pragma unroll
            for (int ni = 0; ni < NI; ++ni) {
                const int n = n0 + wn0 + ni * 16 + (lane & 15);
                const int b = n >> 11, j = n & 2047;
                u16x4 p;
#pragma unroll
                for (int r = 0; r < 4; ++r) p[r] = f2b(acc[mi][ni][r]);
                if (!isV)
                    *(u16x4*)((u16*)C0 + (((long)(b * NH + h)) * TOT + j) * 128 + d) = p;
                else
                    *(u16x4*)((u16*)C1 + (((long)(b * NH + h)) * TOT + j) * 64 + d) = p;
            }
        }
    } else if constexpr (EPI == 5) {          // m = out col, n = token
#pragma unroll
        for (int mi = 0; mi < MI; ++mi) {
            const int m = m0 + wm0 + mi * 16 + quad * 4;
            const float4v bb = *(const float4v*)(F1 + m);
#pragma unroll
            for (int ni = 0; ni < NI; ++ni) {
                const int n = n0 + wn0 + ni * 16 + (lane & 15);
                const float4v xr = *(const float4v*)(F0 + (long)n * DM + m);
                float4v y;
#pragma unroll
                for (int r = 0; r < 4; ++r) y[r] = xr[r] + acc[mi][ni][r] + bb[r];
                *(float4v*)((float*)C0 + (long)n * DM + m) = y;
            }
        }
    }
}

// ---------------------------------------------------------------------------
// Fully register-resident attention passes, QBLK=32. Per wave: its own copy
// of the Q tile in registers (8 dwordx4, loaded ONCE, L2-hot); per tile:
// K slice (4 dwordx4) + V slice to regs; QK/exp/PV entirely in registers.
// ZERO LDS and ZERO barriers in the loop. Grid 2048, XCD-aware decode
// (4 bh per XCD -> K panel L2-resident). DO_PV=0: colsum via shfl+atomics,
// no LDS at all. DO_PV=1: O wave-partials -> small LDS reduce at block end.
// ---------------------------------------------------------------------------
template<int DO_PV>
__global__ __launch_bounds__(256, DO_PV ? 3 : 4)
void attn3(const u16* __restrict__ Abuf, const u16* __restrict__ Bbuf,
           const u16* __restrict__ Vp, float* __restrict__ colsum,
           u16* __restrict__ Opart)
{
    __shared__ float lO[DO_PV ? 32 * 68 : 1];

    // XCD-aware decode: 2048 blocks; xcd = id&7, 4 bh/xcd, 64 blocks/bh
    const int id  = blockIdx.x;
    const int xcd = id & 7;
    const int wi  = id >> 3;                  // 0..255
    const int bh  = xcd + ((wi >> 6) << 3);   // {xcd, xcd+8, xcd+16, xcd+24}
    const int rem = wi & 63;
    const int it  = 31 - (rem & 31);          // longest j-range first
    const int ch  = rem >> 5;

    const int n0 = it * 32;
    const int tid = threadIdx.x, wave = tid >> 6, lane = tid & 63;
    const int l15 = lane & 15, quad = lane >> 4;

    const u16* Qg = Abuf + ((long)bh * CUR + n0) * 128;
    const u16* Kg = Bbuf + (long)bh * TOT * 128;
    const u16* Vg = Vp + (long)bh * DH * TOT;
    float* CS = colsum + (long)bh * TOT;

    // Q tile -> registers, once per wave (loop-invariant by construction)
    bf16x8 qreg[4][2];
#pragma unroll
    for (int c = 0; c < 4; ++c)
#pragma unroll
        for (int smi = 0; smi < 2; ++smi)
            qreg[c][smi] = *(const bf16x8*)(const void*)
                (Qg + (long)(smi * 16 + l15) * 128 + (c * 4 + quad) * 8);

    f32x4 oacc[4][2];
    if constexpr (DO_PV) {
#pragma unroll
        for (int mi = 0; mi < 4; ++mi)
#pragma unroll
            for (int smi = 0; smi < 2; ++smi)
                oacc[mi][smi] = f32x4{0.f, 0.f, 0.f, 0.f};
    }

    const int jw = wave * 16;
    const int nt = ((n0 + 1055) >> 6) + 1;    // tiles with j <= n0+31+PREV
    const int half = (nt + 1) >> 1;
    const int t0 = ch ? half : 0;
    const int t1 = ch ? nt : half;

    for (int t = t0; t < t1; ++t) {
        const int jbase = t * 64 + jw;        // wave's 16-j slice base
        const u16* Krow = Kg + (long)(jbase + l15) * 128 + quad * 8;
        bf16x8 kreg[4];
#pragma unroll
        for (int c = 0; c < 4; ++c)
            kreg[c] = *(const bf16x8*)(const void*)(Krow + c * 32);

        bf16x8 vf[4];
        if constexpr (DO_PV) {
#pragma unroll
            for (int mi = 0; mi < 4; ++mi) {
                const u16x4 vl = *(const u16x4*)(Vg + (long)(mi * 16 + l15) * TOT + jbase + quad * 4);
                const u16x8 vraw = {vl[0], vl[1], vl[2], vl[3], 0, 0, 0, 0};
                vf[mi] = __builtin_bit_cast(bf16x8, vraw);
            }
        }

        // S[j16][i32] = K_slice @ Q  (C row j = quad*4+r, col i = smi*16+l15)
        f32x4 sacc[2];
#pragma unroll
        for (int smi = 0; smi < 2; ++smi) sacc[smi] = f32x4{0.f, 0.f, 0.f, 0.f};
#pragma unroll
        for (int c = 0; c < 4; ++c)
#pragma unroll
            for (int smi = 0; smi < 2; ++smi)
                sacc[smi] = __builtin_amdgcn_mfma_f32_16x16x32_bf16(kreg[c], qreg[c][smi], sacc[smi], 0, 0, 0);

        if constexpr (DO_PV) {
            // P = masked exp(S/8) in-register -> PV via zero-padded k32 MFMA
#pragma unroll
            for (int smi = 0; smi < 2; ++smi) {
                const int ii = n0 + smi * 16 + l15;
                const int jq = jbase + quad * 4;
                u16 p0 = 0, p1 = 0, p2 = 0, p3 = 0;
                if (jq + 0 <= ii + PREV) p0 = f2b(__expf(sacc[smi][0] * 0.125f));
                if (jq + 1 <= ii + PREV) p1 = f2b(__expf(sacc[smi][1] * 0.125f));
                if (jq + 2 <= ii + PREV) p2 = f2b(__expf(sacc[smi][2] * 0.125f));
                if (jq + 3 <= ii + PREV) p3 = f2b(__expf(sacc[smi][3] * 0.125f));
                const u16x8 praw = {p0, p1, p2, p3, 0, 0, 0, 0};
                const bf16x8 pb = __builtin_bit_cast(bf16x8, praw);
#pragma unroll
                for (int mi = 0; mi < 4; ++mi)
                    oacc[mi][smi] = __builtin_amdgcn_mfma_f32_16x16x32_bf16(vf[mi], pb, oacc[mi][smi], 0, 0, 0);
            }
        } else {
            // colsum partials over this block's 32 i for 16 j's
            float cs[4] = {0.f, 0.f, 0.f, 0.f};
            const int jq = jbase + quad * 4;
#pragma unroll
            for (int smi = 0; smi < 2; ++smi) {
                const int ii = n0 + smi * 16 + l15;
#pragma unroll
                for (int r = 0; r < 4; ++r)
                    if (jq + r <= ii + PREV) cs[r] += __expf(sacc[smi][r] * 0.125f);
            }
#pragma unroll
            for (int r = 0; r < 4; ++r) {
                cs[r] += __shfl_xor(cs[r], 1);
                cs[r] += __shfl_xor(cs[r], 2);
                cs[r] += __shfl_xor(cs[r], 4);
                cs[r] += __shfl_xor(cs[r], 8);
            }
            if (l15 == 0) {
                atomicAdd(CS + jq + 0, cs[0]);
                atomicAdd(CS + jq + 1, cs[1]);
                atomicAdd(CS + jq + 2, cs[2]);
                atomicAdd(CS + jq + 3, cs[3]);
            }
        }
    }

    if constexpr (DO_PV) {
        // cross-wave O reduction in LDS (4 barriers per block, epilogue only)
#pragma unroll
        for (int wv = 0; wv < 4; ++wv) {
            if (wave == wv) {
#pragma unroll
                for (int mi = 0; mi < 4; ++mi)
#pragma unroll
                    for (int smi = 0; smi < 2; ++smi) {
                        const int i = smi * 16 + l15, d = mi * 16 + quad * 4;
                        float* p = &lO[i * 68 + d];
                        if (wv == 0) *(f32x4*)p = oacc[mi][smi];
                        else {
                            f32x4 cur = *(const f32x4*)p;
#pragma unroll
                            for (int r = 0; r < 4; ++r) cur[r] += oacc[mi][smi][r];
                            *(f32x4*)p = cur;
                        }
                    }
            }
            __syncthreads();
        }
        const int b = bh >> 4, h = bh & 15;
        u16* Ob = Opart + ((long)(ch * NB + b) * CUR) * DM + h * DH;
#pragma unroll
        for (int k2 = 0; k2 < 2; ++k2) {
            const int idx = k2 * 1024 + tid * 4;
            const int il = idx >> 6, d = idx & 63;
            const f32x4 vv = *(const f32x4*)&lO[il * 68 + d];
            u16x4 o;
#pragma unroll
            for (int r = 0; r < 4; ++r) o[r] = f2b(vv[r]);
            *(u16x4*)(Ob + (long)(n0 + il) * DM + d) = o;
        }
    }
}

// ---------------------------------------------------------------------------
__global__ __launch_bounds__(256)
void combine_O(const u16* __restrict__ O0, const u16* __restrict__ O1,
               u16* __restrict__ Obf)
{
    int i = blockIdx.x * 256 + threadIdx.x;   // over 2048*1024/4 vec4s
    u16x4 a = ((const u16x4*)O0)[i];
    u16x4 c = ((const u16x4*)O1)[i];
    u16x4 o;
#pragma unroll
    for (int r = 0; r < 4; ++r) o[r] = f2b(b2f(a[r]) + b2f(c[r]));
    ((u16x4*)Obf)[i] = o;
}

// ---------------------------------------------------------------------------
__global__ __launch_bounds__(256)
void cvt_weights(const float* __restrict__ Wq, const float* __restrict__ Wkv,
                 const float* __restrict__ Wfc, u16* __restrict__ Wqb,
                 u16* __restrict__ Wkvb, u16* __restrict__ Wfcb)
{
    int i = blockIdx.x * 256 + threadIdx.x;   // 1M vec4s total
    const float* s; u16* d; int off;
    if (i < 262144)      { s = Wq;  d = Wqb;  off = i; }
    else if (i < 786432) { s = Wkv; d = Wkvb; off = i - 262144; }
    else                 { s = Wfc; d = Wfcb; off = i - 786432; }
    float4v f = ((const float4v*)s)[off];
    u16x4 o = {f2b(f[0]), f2b(f[1]), f2b(f[2]), f2b(f[3])};
    ((u16x4*)d)[off] = o;
}

__global__ __launch_bounds__(256)
void pack_H(const float* __restrict__ mem, const float* __restrict__ x, u16* __restrict__ dst)
{
    int i = blockIdx.x * 256 + threadIdx.x;
    int e = i << 2;
    int b = e >> 21, r = e & ((1 << 21) - 1);
    const float* src = (r < (1 << 20)) ? (mem + ((long)b << 20) + r)
                                       : (x + ((long)b << 20) + (r - (1 << 20)));
    float4v f = *(const float4v*)src;
    u16x4 o = {f2b(f[0]), f2b(f[1]), f2b(f[2]), f2b(f[3])};
    ((u16x4*)dst)[i] = o;
}

__global__ __launch_bounds__(256)
void pack_pos(const float* __restrict__ pos, u16* __restrict__ Bbuf)
{
    int i = blockIdx.x * 256 + threadIdx.x;   // (h,j,d/4): 16*2048*16
    int e = i << 2;
    int h = e >> 17, r = e & 131071, j = r >> 6, d = r & 63;
    float4v f = *(const float4v*)(pos + (long)j * DM + h * DH + d);
    u16x4 o = {f2b(f[0]), f2b(f[1]), f2b(f[2]), f2b(f[3])};
    long base = ((long)h * TOT + j) * 128 + 64 + d;
    *(u16x4*)(Bbuf + base) = o;
    *(u16x4*)(Bbuf + base + (long)NH * TOT * 128) = o;
}

__global__ __launch_bounds__(256)
void vprime_kernel(const u16* __restrict__ Vtmp, const float* __restrict__ colsum,
                   u16* __restrict__ Vp)
{
    __shared__ float t[64][65];
    int bz = blockIdx.y;
    int j0 = blockIdx.x * 64;
    const u16* src = Vtmp + ((long)bz * TOT + j0) * 64;
    const float* cs = colsum + (long)bz * TOT + j0;
    for (int e = threadIdx.x; e < 4096; e += 256) {
        int jl = e >> 6, d = e & 63;
        t[jl][d] = b2f(src[e]) / cs[jl];          // fold 1/colsum into V'
    }
    __syncthreads();
    u16* dst = Vp + (long)bz * DH * TOT + j0;
    for (int e = threadIdx.x; e < 4096; e += 256) {
        int d = e >> 6, jl = e & 63;
        dst[(long)d * TOT + jl] = f2b(t[jl][d]);
    }
}

__global__ __launch_bounds__(256)
void ln_kernel(const float* __restrict__ Y, const float* __restrict__ gamma,
               const float* __restrict__ beta, float* __restrict__ out)
{
    const int row = blockIdx.x;
    const float* y = Y + (long)row * DM;
    float v[4];
    float s = 0.f;
#pragma unroll
    for (int t = 0; t < 4; ++t) { v[t] = y[threadIdx.x + t * 256]; s += v[t]; }
#pragma unroll
    for (int off = 32; off > 0; off >>= 1) s += __shfl_down(s, off);
    __shared__ float r1[4], r2[4];
    int wv = threadIdx.x >> 6, ln = threadIdx.x & 63;
    if (ln == 0) r1[wv] = s;
    __syncthreads();
    float mu = (r1[0] + r1[1] + r1[2] + r1[3]) * (1.f / DM);
    float q = 0.f;
#pragma unroll
    for (int t = 0; t < 4; ++t) { float d = v[t] - mu; q += d * d; }
#pragma unroll
    for (int off = 32; off > 0; off >>= 1) q += __shfl_down(q, off);
    if (ln == 0) r2[wv] = q;
    __syncthreads();
    float var = (r2[0] + r2[1] + r2[2] + r2[3]) * (1.f / DM);
    float inv = rsqrtf(var + 1e-5f);
#pragma unroll
    for (int t = 0; t < 4; ++t) {
        int c = threadIdx.x + t * 256;
        out[(long)row * DM + c] = (v[t] - mu) * inv * gamma[c] + beta[c];
    }
}

// ---------------------------------------------------------------------------
extern "C" void kernel_launch(void* const* d_in, const int* in_sizes, int n_in,
                              void* d_out, int out_size, void* d_ws, size_t ws_size,
                              hipStream_t stream)
{
    const float* x     = (const float*)d_in[0];
    const float* pos   = (const float*)d_in[1];
    const float* u     = (const float*)d_in[2];
    const float* vbias = (const float*)d_in[3];
    const float* mem   = (const float*)d_in[4];
    /* d_in[5] = tgt_mask: recomputed analytically (j > i + PREV) */
    const float* Wq    = (const float*)d_in[6];
    const float* Wkv   = (const float*)d_in[7];
    const float* Wfc   = (const float*)d_in[8];
    const float* bfc   = (const float*)d_in[9];
    const float* gamma = (const float*)d_in[10];
    const float* beta  = (const float*)d_in[11];
    float* out = (float*)d_out;

    char* w = (char*)d_ws;
    auto alloc = [&](size_t bytes) {
        char* p = w;
        w += (bytes + 255) & ~(size_t)255;
        return p;
    };
    u16*   Hb     = (u16*)alloc(4096UL * 1024 * 2);       // (b, [mem;x], DM) bf16
    u16*   Wqb    = (u16*)alloc(1024UL * 1024 * 2);
    u16*   Wkvb   = (u16*)alloc(2048UL * 1024 * 2);
    u16*   Wfcb   = (u16*)alloc(1024UL * 1024 * 2);
    u16*   Abuf   = (u16*)alloc(32UL * 1024 * 128 * 2);   // (b,h,i,128): q+u | shift(q+v)
    u16*   Bbuf   = (u16*)alloc(32UL * 2048 * 128 * 2);   // (b,h,j,128): k | pos
    u16*   Vtmp   = (u16*)alloc(32UL * 2048 * 64 * 2);    // (b,h,j,d)
    u16*   Vp     = (u16*)alloc(32UL * 64 * 2048 * 2);    // (b,h,d,j) = v^T / colsum
    float* colsum = (float*)alloc(32UL * 2048 * 4);
    u16*   Opart  = (u16*)alloc(2UL * 2048 * 1024 * 2);   // [chunk][b][i][dm]
    u16*   Obf    = (u16*)alloc(2048UL * 1024 * 2);
    float* Yf     = (float*)alloc(2048UL * 1024 * 4);

    hipMemsetAsync(colsum, 0, 32UL * 2048 * 4, stream);

    cvt_weights<<<4096, 256, 0, stream>>>(Wq, Wkv, Wfc, Wqb, Wkvb, Wfcb);
    pack_H  <<<4096, 256, 0, stream>>>(mem, x, Hb);
    pack_pos<<<2048, 256, 0, stream>>>(pos, Bbuf);

    // Q^T: A=Wq (M=1024 out-ch), B=x tokens (N=1024, z=b) -> Abuf pack
    gemm_bt<128, 64, 64, 64, 32, 1><<<dim3(16, 8, 2), 256, 0, stream>>>(
        Wqb, Hb + 1024UL * 1024, 1024, 1024, 1024, 0, 2048L * 1024, 0,
        Abuf, nullptr, u, vbias);
    // KV^T: A=Wkv (M=2048), B=H (N=4096) -> Bbuf(k)/Vtmp(v)
    gemm_bt<128, 128, 64, 64, 64, 2><<<dim3(32, 16, 1), 256, 0, stream>>>(
        Wkvb, Hb, 2048, 4096, 1024, 0, 0, 0, Bbuf, Vtmp, nullptr, nullptr);

    // pass 0: colsum[bh,j] = sum_i exp(S/8) (masked), all-register loop
    attn3<0><<<dim3(2048), 256, 0, stream>>>(
        Abuf, Bbuf, nullptr, colsum, nullptr);
    // V' = v^T / colsum  (rcs folded here)
    vprime_kernel<<<dim3(32, 32), 256, 0, stream>>>(Vtmp, colsum, Vp);
    // pass 1: fused scores+softmax+PV -> Opart[2], all-register loop
    attn3<1><<<dim3(2048), 256, 0, stream>>>(
        Abuf, Bbuf, Vp, nullptr, Opart);
    // Obf = Opart[0] + Opart[1]
    combine_O<<<2048, 256, 0, stream>>>(Opart, Opart + 2048UL * 1024, Obf);

    // final^T: A=Wfc (M=1024 out-ch), B=Obf (N=2048 tokens) -> Yf = x + C + bfc
    gemm_bt<64, 128, 64, 32, 64, 5><<<dim3(16, 16, 1), 256, 0, stream>>>(
        Wfcb, Obf, 1024, 2048, 1024, 0, 0, 0, Yf, nullptr, x, bfc);
    // LayerNorm -> out
    ln_kernel<<<2048, 256, 0, stream>>>(Yf, gamma, beta, out);
}

// Round 11
// 194.203 us; speedup vs baseline: 1.5304x; 1.5304x over previous
//
#include <hip/hip_runtime.h>
#include <hip/hip_bf16.h>
#include <stdint.h>

typedef unsigned short u16;
typedef __attribute__((ext_vector_type(8))) __bf16 bf16x8;
typedef __attribute__((ext_vector_type(4))) float f32x4;
typedef __attribute__((ext_vector_type(4))) float float4v;
typedef __attribute__((ext_vector_type(4))) u16  u16x4;
typedef __attribute__((ext_vector_type(8))) u16  u16x8;

#define DEV __device__ __forceinline__

#define NB   2
#define CUR  1024
#define PREV 1024
#define TOT  2048
#define DM   1024
#define NH   16
#define DH   64

DEV u16 f2b(float f) {
    uint32_t u = __builtin_bit_cast(uint32_t, f);
    uint32_t r = (u + 0x7fffu + ((u >> 16) & 1u)) >> 16;   // RNE
    return (u16)r;
}
DEV float b2f(u16 u) {
    return __builtin_bit_cast(float, (uint32_t)u << 16);
}

typedef const __attribute__((address_space(1))) void* gptr_t;
typedef __attribute__((address_space(3))) void*       lptr_t;
DEV void async16(const void* g, void* l) {
    __builtin_amdgcn_global_load_lds((gptr_t)g, (lptr_t)l, 16, 0, 0);
}

// ---------------------------------------------------------------------------
// bf16 MFMA GEMM, transposed-output convention (C^T = A[M,K]*B[N,K]^T, M = the
// contiguous output dim). LDS XOR-swizzled via pre-swizzled global source.
// EPI: 1=Q->Abuf(+u,+v,shift)  2=KV->Bbuf/Vtmp  5=final(+x+bfc)->Yf
// ---------------------------------------------------------------------------
template<int BM, int BN, int BK, int WM, int WN, int EPI>
__global__ __launch_bounds__(256)
void gemm_bt(const u16* __restrict__ A, const u16* __restrict__ B,
             int M, int N, int K, long sA, long sB, int bzBase,
             void* __restrict__ C0, void* __restrict__ C1,
             const float* __restrict__ F0, const float* __restrict__ F1)
{
    constexpr int WAVES_N = BN / WN;
    constexpr int MI = WM / 16, NI = WN / 16;
    static_assert((BM / WM) * (BN / WN) == 4, "4 waves");
    static_assert(BK == 64, "swizzle assumes 8 chunks/row");

    __shared__ u16 lA[BM * BK];
    __shared__ u16 lB[BN * BK];

    const int bz = blockIdx.z;
    const int m0 = blockIdx.y * BM, n0 = blockIdx.x * BN;
    const int tid = threadIdx.x, wave = tid >> 6, lane = tid & 63;

    const u16* Ab = A + (long)bz * sA;
    const u16* Bb = B + (long)bz * sB;
    const int wm0 = (wave / WAVES_N) * WM, wn0 = (wave % WAVES_N) * WN;
    const int quad = lane >> 4;

    f32x4 acc[MI][NI];
#pragma unroll
    for (int mi = 0; mi < MI; ++mi)
#pragma unroll
        for (int ni = 0; ni < NI; ++ni)
            acc[mi][ni] = f32x4{0.f, 0.f, 0.f, 0.f};

    const int srow = tid >> 3;
    const int ksw  = (((tid & 7) ^ ((tid >> 3) & 7)) << 3);

    for (int kt = 0; kt < K; kt += BK) {
        __syncthreads();
#pragma unroll
        for (int is = 0; is < (BM * BK) / 2048; ++is) {
            int r = is * 32 + srow;
            async16(Ab + (long)(m0 + r) * K + kt + ksw, &lA[is * 2048 + wave * 512]);
        }
#pragma unroll
        for (int is = 0; is < (BN * BK) / 2048; ++is) {
            int r = is * 32 + srow;
            async16(Bb + (long)(n0 + r) * K + kt + ksw, &lB[is * 2048 + wave * 512]);
        }
        __syncthreads();
#pragma unroll
        for (int ks = 0; ks < BK; ks += 32) {
            bf16x8 af[MI], br[NI];
#pragma unroll
            for (int mi = 0; mi < MI; ++mi)
                af[mi] = *(const bf16x8*)(const void*)
                    &lA[(wm0 + mi * 16 + (lane & 15)) * BK +
                        ((((ks >> 3) + quad) ^ (lane & 7)) << 3)];
#pragma unroll
            for (int ni = 0; ni < NI; ++ni)
                br[ni] = *(const bf16x8*)(const void*)
                    &lB[(wn0 + ni * 16 + (lane & 15)) * BK +
                        ((((ks >> 3) + quad) ^ (lane & 7)) << 3)];
#pragma unroll
            for (int mi = 0; mi < MI; ++mi)
#pragma unroll
                for (int ni = 0; ni < NI; ++ni)
                    acc[mi][ni] = __builtin_amdgcn_mfma_f32_16x16x32_bf16(af[mi], br[ni], acc[mi][ni], 0, 0, 0);
        }
    }

    const int gbz = bzBase + bz;

    if constexpr (EPI == 1) {                 // m = h*64+d, n = token i, bz = b
        u16* Abuf = (u16*)C0;
        const int b = gbz;
#pragma unroll
        for (int mi = 0; mi < MI; ++mi) {
            const int m = m0 + wm0 + mi * 16 + quad * 4;
            const int h = m >> 6, d = m & 63;
            const float4v uu = *(const float4v*)(F0 + m);
            const float4v vv = *(const float4v*)(F1 + m);
#pragma unroll
            for (int ni = 0; ni < NI; ++ni) {
                const int i = n0 + wn0 + ni * 16 + (lane & 15);
                u16x4 pu, pv;
#pragma unroll
                for (int r = 0; r < 4; ++r) {
                    pu[r] = f2b(acc[mi][ni][r] + uu[r]);
                    pv[r] = f2b(acc[mi][ni][r] + vv[r]);
                }
                *(u16x4*)(Abuf + (((long)(b * NH + h)) * CUR + i) * 128 + d) = pu;
                if (b == 0) {
                    if (i > 0)
                        *(u16x4*)(Abuf + (((long)h) * CUR + (i - 1)) * 128 + 64 + d) = pv;
                    if (i == 1023) {
                        u16x4 z = {};
                        *(u16x4*)(Abuf + (((long)h) * CUR + 1023) * 128 + 64 + d) = z;
                    }
                } else {
                    *(u16x4*)(Abuf + (((long)(NH + h)) * CUR + i) * 128 + 64 + d) = pv;
                }
            }
        }
    } else if constexpr (EPI == 2) {          // m = out-ch (k|v), n = b*2048+j
#pragma unroll
        for (int mi = 0; mi < MI; ++mi) {
            const int m = m0 + wm0 + mi * 16 + quad * 4;
            const bool isV = m >= DM;
            const int h = (m >> 6) & 15, d = m & 63;
#pragma unroll
            for (int ni = 0; ni < NI; ++ni) {
                const int n = n0 + wn0 + ni * 16 + (lane & 15);
                const int b = n >> 11, j = n & 2047;
                u16x4 p;
#pragma unroll
                for (int r = 0; r < 4; ++r) p[r] = f2b(acc[mi][ni][r]);
                if (!isV)
                    *(u16x4*)((u16*)C0 + (((long)(b * NH + h)) * TOT + j) * 128 + d) = p;
                else
                    *(u16x4*)((u16*)C1 + (((long)(b * NH + h)) * TOT + j) * 64 + d) = p;
            }
        }
    } else if constexpr (EPI == 5) {          // m = out col, n = token
#pragma unroll
        for (int mi = 0; mi < MI; ++mi) {
            const int m = m0 + wm0 + mi * 16 + quad * 4;
            const float4v bb = *(const float4v*)(F1 + m);
#pragma unroll
            for (int ni = 0; ni < NI; ++ni) {
                const int n = n0 + wn0 + ni * 16 + (lane & 15);
                const float4v xr = *(const float4v*)(F0 + (long)n * DM + m);
                float4v y;
#pragma unroll
                for (int r = 0; r < 4; ++r) y[r] = xr[r] + acc[mi][ni][r] + bb[r];
                *(float4v*)((float*)C0 + (long)n * DM + m) = y;
            }
        }
    }
}

// ---------------------------------------------------------------------------
// Barrier-free attention passes (R8 structure, best measured) + XCD decode:
// id&7 = xcd owns bh in {xcd, xcd+8, xcd+16, xcd+24}; K/Q/Vp L2-resident.
// Wave w privately owns j-slice [t*64+w*16,+16): K straight to registers;
// Q in read-only LDS (ONE barrier); S/P in registers; PV via zero-padded
// 16x16x32 MFMA. DO_PV=0: colsum via shfl+atomics. DO_PV=1: O wave-partials
// -> LDS reduce at block end.
// ---------------------------------------------------------------------------
template<int DO_PV>
__global__ __launch_bounds__(256, 2)
void attn2(const u16* __restrict__ Abuf, const u16* __restrict__ Bbuf,
           const u16* __restrict__ Vp, float* __restrict__ colsum,
           u16* __restrict__ Opart)
{
    __shared__ u16 lQ[64 * 128];
    __shared__ float lO[DO_PV ? 64 * 68 : 1];

    // XCD-aware decode: 1024 blocks; xcd = id&7, 4 bh per xcd, 32 blocks/bh
    const int id  = blockIdx.x;
    const int xcd = id & 7;
    const int wi  = id >> 3;                  // 0..127
    const int bh  = xcd + ((wi >> 5) << 3);   // {xcd, xcd+8, xcd+16, xcd+24}
    const int rem = wi & 31;
    const int it  = 15 - (rem & 15);          // longest j-range first
    const int ch  = rem >> 4;

    const int n0 = it * 64;
    const int tid = threadIdx.x, wave = tid >> 6, lane = tid & 63;
    const int l15 = lane & 15, quad = lane >> 4;

    const u16* Qg = Abuf + ((long)bh * CUR + n0) * 128;
    const u16* Kg = Bbuf + (long)bh * TOT * 128;
    const u16* Vg = Vp + (long)bh * DH * TOT;
    float* CS = colsum + (long)bh * TOT;

    // stage Q once (pre-swizzled source, linear LDS dest)
    {
        const int r4 = tid >> 4, c4 = tid & 15;
        const int csQ = (c4 & 8) | ((c4 & 7) ^ (r4 & 7));
#pragma unroll
        for (int is = 0; is < 4; ++is)
            async16(Qg + (long)(is * 16 + r4) * 128 + csQ * 8, &lQ[is * 2048 + wave * 512]);
    }
    __syncthreads();   // the ONLY barrier before the epilogue

    f32x4 oacc[4][4];
    if constexpr (DO_PV) {
#pragma unroll
        for (int mi = 0; mi < 4; ++mi)
#pragma unroll
            for (int smi = 0; smi < 4; ++smi)
                oacc[mi][smi] = f32x4{0.f, 0.f, 0.f, 0.f};
    }

    const int jw = wave * 16;
    const int nt = it + 17;
    const int half = (nt + 1) >> 1;
    const int t0 = ch ? half : 0;
    const int t1 = ch ? nt : half;

    for (int t = t0; t < t1; ++t) {
        const int jbase = t * 64 + jw;        // wave's 16-j slice base
        // K slice -> registers: A-frag rows j = jbase + l15, k-chunks by quad
        const u16* Krow = Kg + (long)(jbase + l15) * 128 + quad * 8;
        bf16x8 kreg[4];
#pragma unroll
        for (int c = 0; c < 4; ++c)
            kreg[c] = *(const bf16x8*)(const void*)(Krow + c * 32);

        // S[j16][i64] = K_slice @ Q  (C: row j = quad*4+r, col i = smi*16+l15)
        f32x4 sacc[4];
#pragma unroll
        for (int smi = 0; smi < 4; ++smi) sacc[smi] = f32x4{0.f, 0.f, 0.f, 0.f};

        bf16x8 vf[4];
        if constexpr (DO_PV) {
#pragma unroll
            for (int mi = 0; mi < 4; ++mi) {
                const u16x4 vl = *(const u16x4*)(Vg + (long)(mi * 16 + l15) * TOT + jbase + quad * 4);
                const u16x8 vraw = {vl[0], vl[1], vl[2], vl[3], 0, 0, 0, 0};
                vf[mi] = __builtin_bit_cast(bf16x8, vraw);
            }
        }
#pragma unroll
        for (int c = 0; c < 4; ++c) {
            const int cq = c * 4 + quad;
#pragma unroll
            for (int smi = 0; smi < 4; ++smi) {
                const bf16x8 qf = *(const bf16x8*)(const void*)
                    &lQ[(smi * 16 + l15) * 128 + (((cq & 8) | ((cq & 7) ^ (l15 & 7))) << 3)];
                sacc[smi] = __builtin_amdgcn_mfma_f32_16x16x32_bf16(kreg[c], qf, sacc[smi], 0, 0, 0);
            }
        }

        if constexpr (DO_PV) {
            // P = masked exp(S/8) in-register -> PV via zero-padded k32 MFMA
#pragma unroll
            for (int smi = 0; smi < 4; ++smi) {
                const int ii = n0 + smi * 16 + l15;
                const int jq = jbase + quad * 4;
                u16 p0 = 0, p1 = 0, p2 = 0, p3 = 0;
                if (jq + 0 <= ii + PREV) p0 = f2b(__expf(sacc[smi][0] * 0.125f));
                if (jq + 1 <= ii + PREV) p1 = f2b(__expf(sacc[smi][1] * 0.125f));
                if (jq + 2 <= ii + PREV) p2 = f2b(__expf(sacc[smi][2] * 0.125f));
                if (jq + 3 <= ii + PREV) p3 = f2b(__expf(sacc[smi][3] * 0.125f));
                const u16x8 praw = {p0, p1, p2, p3, 0, 0, 0, 0};
                const bf16x8 pb = __builtin_bit_cast(bf16x8, praw);
#pragma unroll
                for (int mi = 0; mi < 4; ++mi)
                    oacc[mi][smi] = __builtin_amdgcn_mfma_f32_16x16x32_bf16(vf[mi], pb, oacc[mi][smi], 0, 0, 0);
            }
        } else {
            // colsum partials: sum over this block's 64 i for 16 j's
            float cs[4] = {0.f, 0.f, 0.f, 0.f};
            const int jq = jbase + quad * 4;
#pragma unroll
            for (int smi = 0; smi < 4; ++smi) {
                const int ii = n0 + smi * 16 + l15;
#pragma unroll
                for (int r = 0; r < 4; ++r)
                    if (jq + r <= ii + PREV) cs[r] += __expf(sacc[smi][r] * 0.125f);
            }
#pragma unroll
            for (int r = 0; r < 4; ++r) {
                cs[r] += __shfl_xor(cs[r], 1);
                cs[r] += __shfl_xor(cs[r], 2);
                cs[r] += __shfl_xor(cs[r], 4);
                cs[r] += __shfl_xor(cs[r], 8);
            }
            if (l15 == 0) {
                atomicAdd(CS + jq + 0, cs[0]);
                atomicAdd(CS + jq + 1, cs[1]);
                atomicAdd(CS + jq + 2, cs[2]);
                atomicAdd(CS + jq + 3, cs[3]);
            }
        }
    }

    if constexpr (DO_PV) {
        // cross-wave O reduction in LDS (4 barriers total per block)
#pragma unroll
        for (int wv = 0; wv < 4; ++wv) {
            if (wave == wv) {
#pragma unroll
                for (int mi = 0; mi < 4; ++mi)
#pragma unroll
                    for (int smi = 0; smi < 4; ++smi) {
                        const int i = smi * 16 + l15, d = mi * 16 + quad * 4;
                        float* p = &lO[i * 68 + d];
                        if (wv == 0) *(f32x4*)p = oacc[mi][smi];
                        else {
                            f32x4 cur = *(const f32x4*)p;
#pragma unroll
                            for (int r = 0; r < 4; ++r) cur[r] += oacc[mi][smi][r];
                            *(f32x4*)p = cur;
                        }
                    }
            }
            __syncthreads();
        }
        const int b = bh >> 4, h = bh & 15;
        u16* Ob = Opart + ((long)(ch * NB + b) * CUR) * DM + h * DH;
#pragma unroll
        for (int k2 = 0; k2 < 4; ++k2) {
            const int idx = k2 * 1024 + tid * 4;
            const int il = idx >> 6, d = idx & 63;
            const f32x4 vv = *(const f32x4*)&lO[il * 68 + d];
            u16x4 o;
#pragma unroll
            for (int r = 0; r < 4; ++r) o[r] = f2b(vv[r]);
            *(u16x4*)(Ob + (long)(n0 + il) * DM + d) = o;
        }
    }
}

// ---------------------------------------------------------------------------
__global__ __launch_bounds__(256)
void combine_O(const u16* __restrict__ O0, const u16* __restrict__ O1,
               u16* __restrict__ Obf)
{
    int i = blockIdx.x * 256 + threadIdx.x;   // over 2048*1024/4 vec4s
    u16x4 a = ((const u16x4*)O0)[i];
    u16x4 c = ((const u16x4*)O1)[i];
    u16x4 o;
#pragma unroll
    for (int r = 0; r < 4; ++r) o[r] = f2b(b2f(a[r]) + b2f(c[r]));
    ((u16x4*)Obf)[i] = o;
}

// ---------------------------------------------------------------------------
// Merged prep: weights cvt (1M vec4) + H pack (1M vec4) + pos pack (0.5M).
// One launch replaces three (saves inter-launch gaps).
// ---------------------------------------------------------------------------
__global__ __launch_bounds__(256)
void prep_all(const float* __restrict__ Wq, const float* __restrict__ Wkv,
              const float* __restrict__ Wfc, const float* __restrict__ mem,
              const float* __restrict__ x, const float* __restrict__ pos,
              u16* __restrict__ Wqb, u16* __restrict__ Wkvb,
              u16* __restrict__ Wfcb, u16* __restrict__ Hb,
              u16* __restrict__ Bbuf)
{
    const long i = (long)blockIdx.x * 256 + threadIdx.x;
    if (i < 1048576) {                        // weights
        const float* s; u16* d; long off;
        if (i < 262144)      { s = Wq;  d = Wqb;  off = i; }
        else if (i < 786432) { s = Wkv; d = Wkvb; off = i - 262144; }
        else                 { s = Wfc; d = Wfcb; off = i - 786432; }
        float4v f = ((const float4v*)s)[off];
        u16x4 o = {f2b(f[0]), f2b(f[1]), f2b(f[2]), f2b(f[3])};
        ((u16x4*)d)[off] = o;
    } else if (i < 2097152) {                 // H = [mem; x] -> bf16
        const long ii = i - 1048576;
        const long e = ii << 2;
        const int b = (int)(e >> 21), r = (int)(e & ((1 << 21) - 1));
        const float* src = (r < (1 << 20)) ? (mem + ((long)b << 20) + r)
                                           : (x + ((long)b << 20) + (r - (1 << 20)));
        float4v f = *(const float4v*)src;
        u16x4 o = {f2b(f[0]), f2b(f[1]), f2b(f[2]), f2b(f[3])};
        ((u16x4*)Hb)[ii] = o;
    } else {                                  // pos -> Bbuf[64:128] (both b)
        const long ii = i - 2097152;
        const long e = ii << 2;
        const int h = (int)(e >> 17), r = (int)(e & 131071), j = r >> 6, d = r & 63;
        float4v f = *(const float4v*)(pos + (long)j * DM + h * DH + d);
        u16x4 o = {f2b(f[0]), f2b(f[1]), f2b(f[2]), f2b(f[3])};
        long base = ((long)h * TOT + j) * 128 + 64 + d;
        *(u16x4*)(Bbuf + base) = o;
        *(u16x4*)(Bbuf + base + (long)NH * TOT * 128) = o;
    }
}

__global__ __launch_bounds__(256)
void vprime_kernel(const u16* __restrict__ Vtmp, const float* __restrict__ colsum,
                   u16* __restrict__ Vp)
{
    __shared__ float t[64][65];
    int bz = blockIdx.y;
    int j0 = blockIdx.x * 64;
    const u16* src = Vtmp + ((long)bz * TOT + j0) * 64;
    const float* cs = colsum + (long)bz * TOT + j0;
    for (int e = threadIdx.x; e < 4096; e += 256) {
        int jl = e >> 6, d = e & 63;
        t[jl][d] = b2f(src[e]) / cs[jl];          // fold 1/colsum into V'
    }
    __syncthreads();
    u16* dst = Vp + (long)bz * DH * TOT + j0;
    for (int e = threadIdx.x; e < 4096; e += 256) {
        int d = e >> 6, jl = e & 63;
        dst[(long)d * TOT + jl] = f2b(t[jl][d]);
    }
}

__global__ __launch_bounds__(256)
void ln_kernel(const float* __restrict__ Y, const float* __restrict__ gamma,
               const float* __restrict__ beta, float* __restrict__ out)
{
    const int row = blockIdx.x;
    const float* y = Y + (long)row * DM;
    float v[4];
    float s = 0.f;
#pragma unroll
    for (int t = 0; t < 4; ++t) { v[t] = y[threadIdx.x + t * 256]; s += v[t]; }
#pragma unroll
    for (int off = 32; off > 0; off >>= 1) s += __shfl_down(s, off);
    __shared__ float r1[4], r2[4];
    int wv = threadIdx.x >> 6, ln = threadIdx.x & 63;
    if (ln == 0) r1[wv] = s;
    __syncthreads();
    float mu = (r1[0] + r1[1] + r1[2] + r1[3]) * (1.f / DM);
    float q = 0.f;
#pragma unroll
    for (int t = 0; t < 4; ++t) { float d = v[t] - mu; q += d * d; }
#pragma unroll
    for (int off = 32; off > 0; off >>= 1) q += __shfl_down(q, off);
    if (ln == 0) r2[wv] = q;
    __syncthreads();
    float var = (r2[0] + r2[1] + r2[2] + r2[3]) * (1.f / DM);
    float inv = rsqrtf(var + 1e-5f);
#pragma unroll
    for (int t = 0; t < 4; ++t) {
        int c = threadIdx.x + t * 256;
        out[(long)row * DM + c] = (v[t] - mu) * inv * gamma[c] + beta[c];
    }
}

// ---------------------------------------------------------------------------
extern "C" void kernel_launch(void* const* d_in, const int* in_sizes, int n_in,
                              void* d_out, int out_size, void* d_ws, size_t ws_size,
                              hipStream_t stream)
{
    const float* x     = (const float*)d_in[0];
    const float* pos   = (const float*)d_in[1];
    const float* u     = (const float*)d_in[2];
    const float* vbias = (const float*)d_in[3];
    const float* mem   = (const float*)d_in[4];
    /* d_in[5] = tgt_mask: recomputed analytically (j > i + PREV) */
    const float* Wq    = (const float*)d_in[6];
    const float* Wkv   = (const float*)d_in[7];
    const float* Wfc   = (const float*)d_in[8];
    const float* bfc   = (const float*)d_in[9];
    const float* gamma = (const float*)d_in[10];
    const float* beta  = (const float*)d_in[11];
    float* out = (float*)d_out;

    char* w = (char*)d_ws;
    auto alloc = [&](size_t bytes) {
        char* p = w;
        w += (bytes + 255) & ~(size_t)255;
        return p;
    };
    u16*   Hb     = (u16*)alloc(4096UL * 1024 * 2);       // (b, [mem;x], DM) bf16
    u16*   Wqb    = (u16*)alloc(1024UL * 1024 * 2);
    u16*   Wkvb   = (u16*)alloc(2048UL * 1024 * 2);
    u16*   Wfcb   = (u16*)alloc(1024UL * 1024 * 2);
    u16*   Abuf   = (u16*)alloc(32UL * 1024 * 128 * 2);   // (b,h,i,128): q+u | shift(q+v)
    u16*   Bbuf   = (u16*)alloc(32UL * 2048 * 128 * 2);   // (b,h,j,128): k | pos
    u16*   Vtmp   = (u16*)alloc(32UL * 2048 * 64 * 2);    // (b,h,j,d)
    u16*   Vp     = (u16*)alloc(32UL * 64 * 2048 * 2);    // (b,h,d,j) = v^T / colsum
    float* colsum = (float*)alloc(32UL * 2048 * 4);
    u16*   Opart  = (u16*)alloc(2UL * 2048 * 1024 * 2);   // [chunk][b][i][dm]
    u16*   Obf    = (u16*)alloc(2048UL * 1024 * 2);
    float* Yf     = (float*)alloc(2048UL * 1024 * 4);

    hipMemsetAsync(colsum, 0, 32UL * 2048 * 4, stream);

    // merged prep: weights + H + pos (one launch)
    prep_all<<<10240, 256, 0, stream>>>(Wq, Wkv, Wfc, mem, x, pos,
                                        Wqb, Wkvb, Wfcb, Hb, Bbuf);

    // Q^T: A=Wq (M=1024 out-ch), B=x tokens (N=1024, z=b) -> Abuf pack
    gemm_bt<128, 64, 64, 64, 32, 1><<<dim3(16, 8, 2), 256, 0, stream>>>(
        Wqb, Hb + 1024UL * 1024, 1024, 1024, 1024, 0, 2048L * 1024, 0,
        Abuf, nullptr, u, vbias);
    // KV^T: A=Wkv (M=2048), B=H (N=4096) -> Bbuf(k)/Vtmp(v)
    gemm_bt<128, 128, 64, 64, 64, 2><<<dim3(32, 16, 1), 256, 0, stream>>>(
        Wkvb, Hb, 2048, 4096, 1024, 0, 0, 0, Bbuf, Vtmp, nullptr, nullptr);

    // pass 0: colsum[bh,j] = sum_i exp(S/8) (masked), barrier-free, XCD-pinned
    attn2<0><<<dim3(1024), 256, 0, stream>>>(
        Abuf, Bbuf, nullptr, colsum, nullptr);
    // V' = v^T / colsum  (rcs folded here)
    vprime_kernel<<<dim3(32, 32), 256, 0, stream>>>(Vtmp, colsum, Vp);
    // pass 1: fused scores+softmax+PV -> Opart[2], barrier-free, XCD-pinned
    attn2<1><<<dim3(1024), 256, 0, stream>>>(
        Abuf, Bbuf, Vp, nullptr, Opart);
    // Obf = Opart[0] + Opart[1]
    combine_O<<<2048, 256, 0, stream>>>(Opart, Opart + 2048UL * 1024, Obf);

    // final^T: A=Wfc (M=1024 out-ch), B=Obf (N=2048 tokens) -> Yf = x + C + bfc
    gemm_bt<64, 128, 64, 32, 64, 5><<<dim3(16, 16, 1), 256, 0, stream>>>(
        Wfcb, Obf, 1024, 2048, 1024, 0, 0, 0, Yf, nullptr, x, bfc);
    // LayerNorm -> out
    ln_kernel<<<2048, 256, 0, stream>>>(Yf, gamma, beta, out);
}